// Round 2
// baseline (129.379 us; speedup 1.0000x reference)
//
#include <hip/hip_runtime.h>
#include <math.h>

#define BN 1024
#define DN 256
#define HN 256
#define KN 8

// ---------------- Kernel A: pairwise squared distances ----------------
// 64x64 tile per block, 256 threads, 4x4 register tile per thread.
// LDS layout: float4 tiles with XOR swizzle p = s ^ ((row>>2)&7) so that
// the 16-distinct-row ds_read_b128 in the inner loop spreads across 8
// bank phases (row stride 128 floats would otherwise alias bank-phase 0).
__global__ __launch_bounds__(256) void k_dist2(const float* __restrict__ x,
                                               float* __restrict__ dist2) {
  __shared__ float4 xi4[64][32];
  __shared__ float4 xj4[64][32];
  const int tid = threadIdx.x;
  const int tx = tid & 15, ty = tid >> 4;
  const int i0 = blockIdx.y << 6, j0 = blockIdx.x << 6;
  float acc[4][4];
#pragma unroll
  for (int m = 0; m < 4; ++m)
#pragma unroll
    for (int n = 0; n < 4; ++n) acc[m][n] = 0.f;

  for (int c = 0; c < 2; ++c) {           // two D-chunks of 128
    __syncthreads();
#pragma unroll
    for (int q = 0; q < 8; ++q) {
      int f = (q << 8) + tid;             // float4 slot 0..2047
      int row = f >> 5;                   // 0..63
      int s = f & 31;                     // float4 column within chunk
      int p = s ^ ((row >> 2) & 7);       // swizzled physical slot
      const float* bi = x + (size_t)(i0 + row) * DN + (c << 7) + (s << 2);
      const float* bj = x + (size_t)(j0 + row) * DN + (c << 7) + (s << 2);
      xi4[row][p] = *reinterpret_cast<const float4*>(bi);
      xj4[row][p] = *reinterpret_cast<const float4*>(bj);
    }
    __syncthreads();
    for (int g = 0; g < 32; ++g) {        // 4 d's per group
      float4 A[4], Bv[4];
      const int pi = g ^ (ty & 7);
      const int pj = g ^ (tx & 7);
#pragma unroll
      for (int m = 0; m < 4; ++m) A[m] = xi4[(ty << 2) + m][pi];
#pragma unroll
      for (int n = 0; n < 4; ++n) Bv[n] = xj4[(tx << 2) + n][pj];
#pragma unroll
      for (int m = 0; m < 4; ++m)
#pragma unroll
        for (int n = 0; n < 4; ++n) {
          float t0 = A[m].x - Bv[n].x;
          float t1 = A[m].y - Bv[n].y;
          float t2 = A[m].z - Bv[n].z;
          float t3 = A[m].w - Bv[n].w;
          acc[m][n] += t0 * t0 + t1 * t1 + t2 * t2 + t3 * t3;
        }
    }
  }
#pragma unroll
  for (int m = 0; m < 4; ++m) {
    float4 o;
    o.x = acc[m][0]; o.y = acc[m][1]; o.z = acc[m][2]; o.w = acc[m][3];
    *reinterpret_cast<float4*>(dist2 + (size_t)(i0 + (ty << 2) + m) * BN +
                               j0 + (tx << 2)) = o;
  }
}

// ---------------- Kernel B: per-row top-K (smallest) ----------------
// Key = (f32 bits << 32) | j  : non-negative floats order as uints,
// ties break toward smaller j (matches lax.top_k). 8 rounds of
// block-min + owner invalidation.
__global__ __launch_bounds__(256) void k_topk(const float* __restrict__ dist2,
                                              int* __restrict__ topk) {
  const int row = blockIdx.x;
  const int tid = threadIdx.x;
  const int lane = tid & 63;
  const int wv = tid >> 6;
  float4 v = *reinterpret_cast<const float4*>(dist2 + (size_t)row * BN + (tid << 2));
  unsigned long long key[4];
  key[0] = ((unsigned long long)__float_as_uint(v.x) << 32) | (unsigned)(tid * 4 + 0);
  key[1] = ((unsigned long long)__float_as_uint(v.y) << 32) | (unsigned)(tid * 4 + 1);
  key[2] = ((unsigned long long)__float_as_uint(v.z) << 32) | (unsigned)(tid * 4 + 2);
  key[3] = ((unsigned long long)__float_as_uint(v.w) << 32) | (unsigned)(tid * 4 + 3);
  __shared__ unsigned long long red[4];
  __shared__ unsigned long long bc;
  for (int r = 0; r < KN; ++r) {
    unsigned long long m = key[0];
    m = key[1] < m ? key[1] : m;
    m = key[2] < m ? key[2] : m;
    m = key[3] < m ? key[3] : m;
#pragma unroll
    for (int off = 32; off > 0; off >>= 1) {
      unsigned long long o = __shfl_down(m, off);
      m = o < m ? o : m;
    }
    if (lane == 0) red[wv] = m;
    __syncthreads();
    if (tid == 0) {
      unsigned long long mm = red[0];
      mm = red[1] < mm ? red[1] : mm;
      mm = red[2] < mm ? red[2] : mm;
      mm = red[3] < mm ? red[3] : mm;
      bc = mm;
      topk[row * KN + r] = (int)(unsigned)(mm & 0xffffffffull);
    }
    __syncthreads();
    unsigned long long mm = bc;
#pragma unroll
    for (int l = 0; l < 4; ++l)
      if (key[l] == mm) key[l] = ~0ull;
  }
}

// ---------------- Kernel C: fused per-row epilogue ----------------
// 4 rows per block (grid 256): W rows read once per 4 output rows.
__global__ __launch_bounds__(256) void k_row(
    const float* __restrict__ x, const float* __restrict__ W_diff,
    const float* __restrict__ b_diff, const float* __restrict__ W_tau,
    const float* __restrict__ b_tau, const float* __restrict__ W_agg,
    const float* __restrict__ b_agg, const float* __restrict__ W_res,
    const float* __restrict__ b_res, const float* __restrict__ gamma,
    const float* __restrict__ beta, const int* __restrict__ topk,
    float* __restrict__ out) {
  const int tid = threadIdx.x;
  const int lane = tid & 63, wv = tid >> 6;
  const int r0 = blockIdx.x << 2;
  __shared__ float s_x[4][HN];
  __shared__ float s_s[4][HN];
  __shared__ float s_hk[4][HN];
  __shared__ float s_y[4][HN];
  __shared__ float s_tau[4];
  __shared__ float s_mu[4], s_rs[4];
  __shared__ int s_idx[4 * KN];

#pragma unroll
  for (int r = 0; r < 4; ++r) s_x[r][tid] = x[(size_t)(r0 + r) * DN + tid];
  if (tid < 4 * KN) s_idx[tid] = topk[r0 * KN + tid];
  __syncthreads();

  // sum of |x_i - x_j| over the K neighbors, per dimension
#pragma unroll
  for (int r = 0; r < 4; ++r) {
    float xv = s_x[r][tid];
    float s = 0.f;
#pragma unroll
    for (int k = 0; k < KN; ++k) {
      int j = s_idx[r * KN + k];
      s += fabsf(xv - x[(size_t)j * DN + tid]);
    }
    s_s[r][tid] = s;
  }
  // tau: wave wv reduces row wv
  {
    float p = 0.f;
#pragma unroll
    for (int q = 0; q < DN / 64; ++q) {
      int d = lane + (q << 6);
      p += s_x[wv][d] * W_tau[d];
    }
#pragma unroll
    for (int off = 32; off > 0; off >>= 1) p += __shfl_down(p, off);
    if (lane == 0) {
      float z = p + b_tau[0];
      float sp = z > 0.f ? z + log1pf(expf(-z)) : log1pf(expf(z));
      s_tau[wv] = fmaxf(sp, 0.01f) + 1.0f;
    }
  }
  __syncthreads();  // covers s_s and s_tau

  // matvec 1: h_k = (mean_k proj + b_diff) / tau
  {
    float a0 = 0.f, a1 = 0.f, a2 = 0.f, a3 = 0.f;
    const float* wrow = W_diff + (size_t)tid * DN;
    for (int d = 0; d < DN; d += 4) {
      float4 w4 = *reinterpret_cast<const float4*>(wrow + d);
      float4 s0 = *reinterpret_cast<const float4*>(&s_s[0][d]);
      float4 s1 = *reinterpret_cast<const float4*>(&s_s[1][d]);
      float4 s2 = *reinterpret_cast<const float4*>(&s_s[2][d]);
      float4 s3 = *reinterpret_cast<const float4*>(&s_s[3][d]);
      a0 += s0.x * w4.x + s0.y * w4.y + s0.z * w4.z + s0.w * w4.w;
      a1 += s1.x * w4.x + s1.y * w4.y + s1.z * w4.z + s1.w * w4.w;
      a2 += s2.x * w4.x + s2.y * w4.y + s2.z * w4.z + s2.w * w4.w;
      a3 += s3.x * w4.x + s3.y * w4.y + s3.z * w4.z + s3.w * w4.w;
    }
    float bd = b_diff[tid];
    s_hk[0][tid] = (a0 * 0.125f + bd) / s_tau[0];
    s_hk[1][tid] = (a1 * 0.125f + bd) / s_tau[1];
    s_hk[2][tid] = (a2 * 0.125f + bd) / s_tau[2];
    s_hk[3][tid] = (a3 * 0.125f + bd) / s_tau[3];
  }
  __syncthreads();

  // matvec 2 (W_agg on h_k) + matvec 3 (W_res on x), relu + residual
  {
    float a0 = 0.f, a1 = 0.f, a2 = 0.f, a3 = 0.f;
    float p0 = 0.f, p1 = 0.f, p2 = 0.f, p3 = 0.f;
    const float* wa = W_agg + (size_t)tid * HN;
    const float* wr = W_res + (size_t)tid * DN;
    for (int d = 0; d < DN; d += 4) {
      float4 va = *reinterpret_cast<const float4*>(wa + d);
      float4 vr = *reinterpret_cast<const float4*>(wr + d);
      float4 h0 = *reinterpret_cast<const float4*>(&s_hk[0][d]);
      float4 h1 = *reinterpret_cast<const float4*>(&s_hk[1][d]);
      float4 h2 = *reinterpret_cast<const float4*>(&s_hk[2][d]);
      float4 h3 = *reinterpret_cast<const float4*>(&s_hk[3][d]);
      float4 x0 = *reinterpret_cast<const float4*>(&s_x[0][d]);
      float4 x1 = *reinterpret_cast<const float4*>(&s_x[1][d]);
      float4 x2 = *reinterpret_cast<const float4*>(&s_x[2][d]);
      float4 x3 = *reinterpret_cast<const float4*>(&s_x[3][d]);
      a0 += h0.x * va.x + h0.y * va.y + h0.z * va.z + h0.w * va.w;
      a1 += h1.x * va.x + h1.y * va.y + h1.z * va.z + h1.w * va.w;
      a2 += h2.x * va.x + h2.y * va.y + h2.z * va.z + h2.w * va.w;
      a3 += h3.x * va.x + h3.y * va.y + h3.z * va.z + h3.w * va.w;
      p0 += x0.x * vr.x + x0.y * vr.y + x0.z * vr.z + x0.w * vr.w;
      p1 += x1.x * vr.x + x1.y * vr.y + x1.z * vr.z + x1.w * vr.w;
      p2 += x2.x * vr.x + x2.y * vr.y + x2.z * vr.z + x2.w * vr.w;
      p3 += x3.x * vr.x + x3.y * vr.y + x3.z * vr.z + x3.w * vr.w;
    }
    float ba = b_agg[tid], br = b_res[tid];
    s_y[0][tid] = fmaxf(a0 + ba, 0.f) + p0 + br;
    s_y[1][tid] = fmaxf(a1 + ba, 0.f) + p1 + br;
    s_y[2][tid] = fmaxf(a2 + ba, 0.f) + p2 + br;
    s_y[3][tid] = fmaxf(a3 + ba, 0.f) + p3 + br;
  }
  __syncthreads();

  // LayerNorm stats: wave wv reduces row wv
  {
    float sum = 0.f, sq = 0.f;
#pragma unroll
    for (int q = 0; q < HN / 64; ++q) {
      float v = s_y[wv][lane + (q << 6)];
      sum += v;
      sq += v * v;
    }
#pragma unroll
    for (int off = 32; off > 0; off >>= 1) {
      sum += __shfl_down(sum, off);
      sq += __shfl_down(sq, off);
    }
    if (lane == 0) {
      float mu = sum * (1.f / HN);
      float var = sq * (1.f / HN) - mu * mu;
      s_mu[wv] = mu;
      s_rs[wv] = 1.f / sqrtf(var + 1e-5f);
    }
  }
  __syncthreads();

  float g = gamma[tid], be = beta[tid];
#pragma unroll
  for (int r = 0; r < 4; ++r) {
    out[(size_t)(r0 + r) * HN + tid] =
        (s_y[r][tid] - s_mu[r]) * s_rs[r] * g + be;
  }
}

extern "C" void kernel_launch(void* const* d_in, const int* in_sizes, int n_in,
                              void* d_out, int out_size, void* d_ws,
                              size_t ws_size, hipStream_t stream) {
  const float* x = (const float*)d_in[0];
  const float* W_diff = (const float*)d_in[1];
  const float* b_diff = (const float*)d_in[2];
  const float* W_tau = (const float*)d_in[3];
  const float* b_tau = (const float*)d_in[4];
  const float* W_agg = (const float*)d_in[5];
  const float* b_agg = (const float*)d_in[6];
  const float* W_res = (const float*)d_in[7];
  const float* b_res = (const float*)d_in[8];
  const float* gamma = (const float*)d_in[9];
  const float* beta = (const float*)d_in[10];
  float* out = (float*)d_out;

  float* dist2 = (float*)d_ws;
  int* topk = (int*)((char*)d_ws + (size_t)BN * BN * sizeof(float));

  dim3 gA(BN / 64, BN / 64);
  k_dist2<<<gA, 256, 0, stream>>>(x, dist2);
  k_topk<<<BN, 256, 0, stream>>>(dist2, topk);
  k_row<<<BN / 4, 256, 0, stream>>>(x, W_diff, b_diff, W_tau, b_tau, W_agg,
                                    b_agg, W_res, b_res, gamma, beta, topk,
                                    out);
}